// Round 9
// baseline (92.037 us; speedup 1.0000x reference)
//
#include <hip/hip_runtime.h>

#define HH 128
#define WW 128
#define RING 73728            // ring base: wbuf occupies [0, 73728)
#define ROWB 8704             // ring row stride: 68 cols * 128 B

typedef __bf16 bf16x8 __attribute__((ext_vector_type(8)));
typedef __bf16 bf16x2 __attribute__((ext_vector_type(2)));
typedef float f32x4 __attribute__((ext_vector_type(4)));

static __device__ __forceinline__ unsigned short f2bf(float f) {
  unsigned int u = __float_as_uint(f);
  u = (u + 0x7FFFu + ((u >> 16) & 1u)) >> 16;  // RNE
  return (unsigned short)u;
}

static __device__ __forceinline__ unsigned int pack2bf(float lo, float hi) {
  bf16x2 v;
  v[0] = (__bf16)lo;
  v[1] = (__bf16)hi;
  return __builtin_bit_cast(unsigned int, v);
}

// ---------------------------------------------------------------------------
// Prep 1: pack conv_w [co][ci][tap] into MFMA A-fragment order (bf16):
//   wfrag[f = h*9+tap][cotile][lane][i] = conv_w[cotile*16 + lane%16]
//                                               [h*32 + (lane/16)*8 + i][tap]
// ---------------------------------------------------------------------------
__global__ __launch_bounds__(256) void prep_wfrag(const float* __restrict__ conv_w,
                                                  unsigned short* __restrict__ wfrag) {
  int tid = blockIdx.x * 256 + threadIdx.x;
  if (tid >= 18 * 2048) return;
  int i    = tid & 7;
  int lane = (tid >> 3) & 63;
  int cot  = (tid >> 9) & 3;
  int f    = tid >> 11;           // 0..17
  int h    = f / 9;               // ci half
  int tap  = f - h * 9;
  int co   = cot * 16 + (lane & 15);
  int ci   = h * 32 + (lane >> 4) * 8 + i;
  wfrag[tid] = f2bf(conv_w[(co * 64 + ci) * 9 + tap]);
}

// ---------------------------------------------------------------------------
// Prep 2: grouped conv of spatially-constant input -> 9-case boundary table
//   ext[b][co][cy][cx]  (includes conv_b + extra_b)
// ---------------------------------------------------------------------------
__global__ __launch_bounds__(256) void prep_ext(const float* __restrict__ extra_in,
                                                const float* __restrict__ extra_w,
                                                const float* __restrict__ conv_b,
                                                const float* __restrict__ extra_b,
                                                float* __restrict__ ext) {
  int t = blockIdx.x * 256 + threadIdx.x;
  if (t >= 32 * 64) return;
  int b = t >> 6, co = t & 63;
  float base = conv_b[co] + extra_b[co];
  float acc[3][3];
#pragma unroll
  for (int i = 0; i < 3; ++i)
#pragma unroll
    for (int j = 0; j < 3; ++j) acc[i][j] = 0.f;

#pragma unroll
  for (int f = 0; f < 3; ++f) {
    float e = extra_in[b * 192 + co * 3 + f];
    const float* w = extra_w + (co * 3 + f) * 9;
    float rs[3][3];
#pragma unroll
    for (int ky = 0; ky < 3; ++ky) {
      float w0 = w[ky * 3 + 0], w1 = w[ky * 3 + 1], w2 = w[ky * 3 + 2];
      rs[ky][0] = w1 + w2;
      rs[ky][1] = w0 + w1 + w2;
      rs[ky][2] = w0 + w1;
    }
#pragma unroll
    for (int cx = 0; cx < 3; ++cx) {
      acc[0][cx] += e * (rs[1][cx] + rs[2][cx]);
      acc[1][cx] += e * (rs[0][cx] + rs[1][cx] + rs[2][cx]);
      acc[2][cx] += e * (rs[0][cx] + rs[1][cx]);
    }
  }
#pragma unroll
  for (int cy = 0; cy < 3; ++cy)
#pragma unroll
    for (int cx = 0; cx < 3; ++cx)
      ext[t * 9 + cy * 3 + cx] = base + acc[cy][cx];
}

// ---------------------------------------------------------------------------
// Main: strip-persistent implicit-GEMM conv (mfma_f32_16x16x32_bf16).
// Block = (batch, x-half 64 cols, 16-row strip) = 4 tiles of 4 rows.
// 256 thr = 4 waves, wave = row-in-tile. 1 block/CU (140 KB LDS).
//  - wbuf [18 f][4 cot][64 lane][16B] = 72 KB, DMA'd ONCE per strip
//    (global_load_lds 16B) -> compute is LDS-only, no vmcnt in MFMA path.
//  - input ring: 8 rows x [68 c][64 ci] bf16 (69.6 KB), 6 live; each tile
//    stages only 4 NEW rows (halo ratio 1.125 vs 1.5).
//  - T14 split: next tile's float2 loads issue into regs BEFORE compute
//    (latency hides under 288 MFMAs); cvt+ds_write after the barrier.
//  - swizzle: byte ^= (c&7)<<4 spreads the 128B ci-run -> 2-way on ds_read.
//  - direct scalar stores (clean WRITE now that in-loop L2 reads are gone).
// ---------------------------------------------------------------------------
__global__ __launch_bounds__(256, 1) void conv_strip(const float* __restrict__ x,
                                                     const unsigned short* __restrict__ wfrag,
                                                     const float* __restrict__ ext,
                                                     float* __restrict__ out) {
  const int b     = blockIdx.z;
  const int ybase = blockIdx.y * 16;
  const int x0    = blockIdx.x * 64;
  const int tid  = threadIdx.x;
  const int lane = tid & 63;
  const int wv   = tid >> 6;
  const int pix  = lane & 15;
  const int g    = lane >> 4;

  __shared__ __align__(16) unsigned char lds[RING + 8 * ROWB];  // 143360 B

  const float* xb = x + (size_t)b * 64 * HH * WW;

  // ---- weights: DMA 72 KB once ----
#pragma unroll
  for (int it = 0; it < 18; ++it) {
    int off = (tid + it * 256) * 16;
    __builtin_amdgcn_global_load_lds(
        (const __attribute__((address_space(1))) unsigned int*)((const char*)wfrag + off),
        (__attribute__((address_space(3))) unsigned int*)(lds + off), 16, 0, 0);
  }

  // ---- prologue: stage rows gy = ybase-1 .. ybase+4 (6 rows) ----
#pragma unroll
  for (int it = 0; it < 6; ++it) {
    int q   = tid + it * 256;        // 0..1535
    int cp  = q & 31;
    int cig = (q >> 5) & 7;
    int r   = q >> 8;                // 0..5
    int gy  = ybase - 1 + r;
    int c   = 1 + 2 * cp;
    int x_in = x0 + 2 * cp;
    unsigned int pkA[4] = {0u, 0u, 0u, 0u};
    unsigned int pkB[4] = {0u, 0u, 0u, 0u};
    if ((unsigned)gy < 128u) {
      const float* src = xb + (size_t)(cig * 8) * (HH * WW) + gy * WW + x_in;
      float2 f[8];
#pragma unroll
      for (int j = 0; j < 8; ++j) f[j] = *(const float2*)(src + (size_t)j * (HH * WW));
#pragma unroll
      for (int w = 0; w < 4; ++w) {
        pkA[w] = pack2bf(f[2 * w].x, f[2 * w + 1].x);
        pkB[w] = pack2bf(f[2 * w].y, f[2 * w + 1].y);
      }
    }
    int slot = (gy + 1) & 7;
    int baseA = (RING + slot * ROWB + c * 128 + cig * 16) ^ ((c & 7) << 4);
    int baseB = (RING + slot * ROWB + (c + 1) * 128 + cig * 16) ^ (((c + 1) & 7) << 4);
    *(uint4*)(lds + baseA) = make_uint4(pkA[0], pkA[1], pkA[2], pkA[3]);
    *(uint4*)(lds + baseB) = make_uint4(pkB[0], pkB[1], pkB[2], pkB[3]);
  }
  if (tid < 96) {  // border cols c in {0,65}
    int c01 = tid & 1;
    int cig = (tid >> 1) & 7;
    int r   = tid >> 4;              // 0..5
    int gy  = ybase - 1 + r;
    int c   = c01 ? 65 : 0;
    int x_in = x0 - 1 + c;
    bool inb = ((unsigned)gy < 128u) & ((unsigned)x_in < 128u);
    unsigned int pk[4] = {0u, 0u, 0u, 0u};
    if (inb) {
      const float* src = xb + (size_t)(cig * 8) * (HH * WW) + gy * WW + x_in;
      float v[8];
#pragma unroll
      for (int j = 0; j < 8; ++j) v[j] = src[(size_t)j * (HH * WW)];
#pragma unroll
      for (int w = 0; w < 4; ++w) pk[w] = pack2bf(v[2 * w], v[2 * w + 1]);
    }
    int byte = (RING + ((gy + 1) & 7) * ROWB + c * 128 + cig * 16) ^ ((c & 7) << 4);
    *(uint4*)(lds + byte) = make_uint4(pk[0], pk[1], pk[2], pk[3]);
  }
  __syncthreads();

  const float* extb = ext + (size_t)b * 64 * 9;

#pragma unroll 1
  for (int t = 0; t < 4; ++t) {
    const int yt = ybase + 4 * t;

    // ---- A) prefetch next tile's 4 rows into registers (fire & forget) ----
    float2 pre[4][8];
    float  bpre[8];
    if (t < 3) {
#pragma unroll
      for (int it = 0; it < 4; ++it) {
        int q   = tid + it * 256;    // 0..1023
        int cp  = q & 31;
        int cig = (q >> 5) & 7;
        int r   = q >> 8;            // 0..3
        int gy  = yt + 5 + r;
        int x_in = x0 + 2 * cp;
        if ((unsigned)gy < 128u) {
          const float* src = xb + (size_t)(cig * 8) * (HH * WW) + gy * WW + x_in;
#pragma unroll
          for (int j = 0; j < 8; ++j) pre[it][j] = *(const float2*)(src + (size_t)j * (HH * WW));
        } else {
#pragma unroll
          for (int j = 0; j < 8; ++j) pre[it][j] = make_float2(0.f, 0.f);
        }
      }
      if (tid < 64) {
        int c01 = tid & 1;
        int cig = (tid >> 1) & 7;
        int r   = tid >> 4;          // 0..3
        int gy  = yt + 5 + r;
        int c   = c01 ? 65 : 0;
        int x_in = x0 - 1 + c;
        bool inb = ((unsigned)gy < 128u) & ((unsigned)x_in < 128u);
#pragma unroll
        for (int j = 0; j < 8; ++j)
          bpre[j] = inb ? xb[(size_t)(cig * 8 + j) * (HH * WW) + gy * WW + x_in] : 0.f;
      }
    }

    // ---- B) compute tile (LDS only) ----
    f32x4 acc[4][4];
#pragma unroll
    for (int i = 0; i < 4; ++i)
#pragma unroll
      for (int j = 0; j < 4; ++j) acc[i][j] = (f32x4){0.f, 0.f, 0.f, 0.f};

#pragma unroll
    for (int h = 0; h < 2; ++h) {
#pragma unroll
      for (int tap = 0; tap < 9; ++tap) {
        const int ky = tap / 3, kx = tap - ky * 3;
        const int fidx = h * 9 + tap;
        bf16x8 af[4];
#pragma unroll
        for (int cot = 0; cot < 4; ++cot)
          af[cot] = *(const bf16x8*)(lds + fidx * 4096 + cot * 1024 + lane * 16);
        bf16x8 pf[4];
        const int slot = (yt + wv + ky) & 7;  // gy = yt+wv+ky-1 -> slot gy+1
#pragma unroll
        for (int m = 0; m < 4; ++m) {
          int c = m * 16 + pix + kx;
          int byte = (RING + slot * ROWB + c * 128 + h * 64 + g * 16) ^ ((c & 7) << 4);
          pf[m] = *(const bf16x8*)(lds + byte);
        }
#pragma unroll
        for (int cot = 0; cot < 4; ++cot)
#pragma unroll
          for (int m = 0; m < 4; ++m)
            acc[cot][m] = __builtin_amdgcn_mfma_f32_16x16x32_bf16(af[cot], pf[m],
                                                                  acc[cot][m], 0, 0, 0);
      }
    }

    // ---- C) store tile (direct, coalesced within 16-lane groups) ----
    const int y  = yt + wv;
    const int cy = (y == 0) ? 0 : ((y == HH - 1) ? 2 : 1);
#pragma unroll
    for (int cot = 0; cot < 4; ++cot) {
#pragma unroll
      for (int m = 0; m < 4; ++m) {
        int xg = x0 + m * 16 + pix;
        int cx = (xg == 0) ? 0 : ((xg == WW - 1) ? 2 : 1);
#pragma unroll
        for (int j = 0; j < 4; ++j) {
          int co = cot * 16 + g * 4 + j;
          out[(((size_t)b * 64 + co) * HH + y) * WW + xg] =
              acc[cot][m][j] + extb[co * 9 + cy * 3 + cx];
        }
      }
    }

    __syncthreads();  // all waves done reading ring rows for tile t

    // ---- D) commit prefetched rows to the ring ----
    if (t < 3) {
#pragma unroll
      for (int it = 0; it < 4; ++it) {
        int q   = tid + it * 256;
        int cp  = q & 31;
        int cig = (q >> 5) & 7;
        int r   = q >> 8;
        int gy  = yt + 5 + r;
        int c   = 1 + 2 * cp;
        unsigned int pkA[4], pkB[4];
#pragma unroll
        for (int w = 0; w < 4; ++w) {
          pkA[w] = pack2bf(pre[it][2 * w].x, pre[it][2 * w + 1].x);
          pkB[w] = pack2bf(pre[it][2 * w].y, pre[it][2 * w + 1].y);
        }
        int slot = (gy + 1) & 7;
        int baseA = (RING + slot * ROWB + c * 128 + cig * 16) ^ ((c & 7) << 4);
        int baseB = (RING + slot * ROWB + (c + 1) * 128 + cig * 16) ^ (((c + 1) & 7) << 4);
        *(uint4*)(lds + baseA) = make_uint4(pkA[0], pkA[1], pkA[2], pkA[3]);
        *(uint4*)(lds + baseB) = make_uint4(pkB[0], pkB[1], pkB[2], pkB[3]);
      }
      if (tid < 64) {
        int c01 = tid & 1;
        int cig = (tid >> 1) & 7;
        int r   = tid >> 4;
        int gy  = yt + 5 + r;
        int c   = c01 ? 65 : 0;
        unsigned int pk[4];
#pragma unroll
        for (int w = 0; w < 4; ++w) pk[w] = pack2bf(bpre[2 * w], bpre[2 * w + 1]);
        int byte = (RING + ((gy + 1) & 7) * ROWB + c * 128 + cig * 16) ^ ((c & 7) << 4);
        *(uint4*)(lds + byte) = make_uint4(pk[0], pk[1], pk[2], pk[3]);
      }
      __syncthreads();
    }
  }
}

extern "C" void kernel_launch(void* const* d_in, const int* in_sizes, int n_in,
                              void* d_out, int out_size, void* d_ws, size_t ws_size,
                              hipStream_t stream) {
  const float* x        = (const float*)d_in[0];
  const float* extra_in = (const float*)d_in[1];
  const float* conv_w   = (const float*)d_in[2];
  const float* conv_b   = (const float*)d_in[3];
  const float* extra_w  = (const float*)d_in[4];
  const float* extra_b  = (const float*)d_in[5];
  float* out = (float*)d_out;

  unsigned short* wfrag = (unsigned short*)d_ws;              // 73728 B
  float* ext = (float*)((char*)d_ws + 73728);                 // 73728 B

  hipLaunchKernelGGL(prep_wfrag, dim3(144), dim3(256), 0, stream, conv_w, wfrag);
  hipLaunchKernelGGL(prep_ext,   dim3(8),   dim3(256), 0, stream,
                     extra_in, extra_w, conv_b, extra_b, ext);
  hipLaunchKernelGGL(conv_strip, dim3(2, 8, 32), dim3(256), 0, stream,
                     x, wfrag, ext, out);
}

// Round 10
// 86.569 us; speedup vs baseline: 1.0632x; 1.0632x over previous
//
#include <hip/hip_runtime.h>

#define HH 128
#define WW 128
#define SB0 73728              // sbuf region base (wbuf occupies [0, 73728))
#define SBN 26112              // per-buffer bytes: [6 r][68 c][32 ci] bf16

typedef __bf16 bf16x8 __attribute__((ext_vector_type(8)));
typedef __bf16 bf16x2 __attribute__((ext_vector_type(2)));
typedef float f32x4 __attribute__((ext_vector_type(4)));

static __device__ __forceinline__ unsigned short f2bf(float f) {
  unsigned int u = __float_as_uint(f);
  u = (u + 0x7FFFu + ((u >> 16) & 1u)) >> 16;  // RNE
  return (unsigned short)u;
}

static __device__ __forceinline__ unsigned int pack2bf(float lo, float hi) {
  bf16x2 v;
  v[0] = (__bf16)lo;
  v[1] = (__bf16)hi;
  return __builtin_bit_cast(unsigned int, v);
}

// ---------------------------------------------------------------------------
// Prep 1: pack conv_w [co][ci][tap] into MFMA A-fragment order (bf16):
//   wfrag[f = h*9+tap][cotile][lane][i] = conv_w[cotile*16 + lane%16]
//                                               [h*32 + (lane/16)*8 + i][tap]
// ---------------------------------------------------------------------------
__global__ __launch_bounds__(256) void prep_wfrag(const float* __restrict__ conv_w,
                                                  unsigned short* __restrict__ wfrag) {
  int tid = blockIdx.x * 256 + threadIdx.x;
  if (tid >= 18 * 2048) return;
  int i    = tid & 7;
  int lane = (tid >> 3) & 63;
  int cot  = (tid >> 9) & 3;
  int f    = tid >> 11;           // 0..17
  int h    = f / 9;               // ci half
  int tap  = f - h * 9;
  int co   = cot * 16 + (lane & 15);
  int ci   = h * 32 + (lane >> 4) * 8 + i;
  wfrag[tid] = f2bf(conv_w[(co * 64 + ci) * 9 + tap]);
}

// ---------------------------------------------------------------------------
// Prep 2: grouped conv of spatially-constant input -> 9-case boundary table
//   ext[b][co][cy][cx]  (includes conv_b + extra_b)
// ---------------------------------------------------------------------------
__global__ __launch_bounds__(256) void prep_ext(const float* __restrict__ extra_in,
                                                const float* __restrict__ extra_w,
                                                const float* __restrict__ conv_b,
                                                const float* __restrict__ extra_b,
                                                float* __restrict__ ext) {
  int t = blockIdx.x * 256 + threadIdx.x;
  if (t >= 32 * 64) return;
  int b = t >> 6, co = t & 63;
  float base = conv_b[co] + extra_b[co];
  float acc[3][3];
#pragma unroll
  for (int i = 0; i < 3; ++i)
#pragma unroll
    for (int j = 0; j < 3; ++j) acc[i][j] = 0.f;

#pragma unroll
  for (int f = 0; f < 3; ++f) {
    float e = extra_in[b * 192 + co * 3 + f];
    const float* w = extra_w + (co * 3 + f) * 9;
    float rs[3][3];
#pragma unroll
    for (int ky = 0; ky < 3; ++ky) {
      float w0 = w[ky * 3 + 0], w1 = w[ky * 3 + 1], w2 = w[ky * 3 + 2];
      rs[ky][0] = w1 + w2;
      rs[ky][1] = w0 + w1 + w2;
      rs[ky][2] = w0 + w1;
    }
#pragma unroll
    for (int cx = 0; cx < 3; ++cx) {
      acc[0][cx] += e * (rs[1][cx] + rs[2][cx]);
      acc[1][cx] += e * (rs[0][cx] + rs[1][cx] + rs[2][cx]);
      acc[2][cx] += e * (rs[0][cx] + rs[1][cx]);
    }
  }
#pragma unroll
  for (int cy = 0; cy < 3; ++cy)
#pragma unroll
    for (int cx = 0; cx < 3; ++cx)
      ext[t * 9 + cy * 3 + cx] = base + acc[cy][cx];
}

// ---------------------------------------------------------------------------
// Main: producer/consumer group ping-pong implicit-GEMM conv.
// Block = (batch, x-half, 32-row strip) = 8 chunks x 4 rows; 512 thr = 2
// groups x 4 waves. Group G computes chunks with (c&1)==G; while one group
// computes phase p=(2c+h) from buf[p%3], the other stages ITS next chunk's
// half into buf[(p+2)%3] (freed at the barrier ending phase p-1). Every
// phase: 4 waves on MFMA/LDS + 4 waves on HBM -> max() not sum().
// Weights: 72 KB DMA'd once per block (global_load_lds 16B); compute path
// is LDS-only (no vmcnt in the MFMA chain). Direct stores after h=1 (clean
// WRITE per r9 evidence). Swizzle: byte ^= ((c^(c>>2))&3)<<4 (2-way = free).
// ---------------------------------------------------------------------------
__global__ __launch_bounds__(512, 1) void conv_pc(const float* __restrict__ x,
                                                  const unsigned short* __restrict__ wfrag,
                                                  const float* __restrict__ ext,
                                                  float* __restrict__ out) {
  const int b     = blockIdx.z;
  const int ybase = blockIdx.y * 32;
  const int x0    = blockIdx.x * 64;
  const int tid  = threadIdx.x;
  const int lane = tid & 63;
  const int wv8  = tid >> 6;        // 0..7
  const int grp  = wv8 >> 2;        // 0 = A, 1 = B
  const int wv   = wv8 & 3;         // row within chunk
  const int gtid = tid & 255;       // thread id within group
  const int pix  = lane & 15;
  const int g    = lane >> 4;

  __shared__ __align__(16) unsigned char lds[SB0 + 3 * SBN];  // 152064 B

  const float* xb   = x + (size_t)b * 64 * HH * WW;
  const float* extb = ext + (size_t)b * 64 * 9;

  // ---- weights: DMA 72 KB once (9 iters x 512 thr x 16B) ----
#pragma unroll
  for (int it = 0; it < 9; ++it) {
    int off = (tid + it * 512) * 16;
    __builtin_amdgcn_global_load_lds(
        (const __attribute__((address_space(1))) unsigned int*)((const char*)wfrag + off),
        (__attribute__((address_space(3))) unsigned int*)(lds + off), 16, 0, 0);
  }

  // ---- stage (chunk c, ci-half h) -> sbuf[buf], using one group's 256 thr ----
  auto stage_to = [&](int buf, int c, int h) {
    unsigned char* sb = lds + SB0 + buf * SBN;
    // interior: col pairs (1+2cp, 2+2cp); 768 items = 3 x 256
#pragma unroll
    for (int it = 0; it < 3; ++it) {
      int q   = gtid + it * 256;
      int cp  = q & 31;
      int cig = (q >> 5) & 3;
      int r   = q >> 7;            // 0..5
      int gy  = ybase + 4 * c - 1 + r;
      int cc  = 1 + 2 * cp;
      int x_in = x0 + 2 * cp;
      unsigned int pkA[4] = {0u, 0u, 0u, 0u};
      unsigned int pkB[4] = {0u, 0u, 0u, 0u};
      if ((unsigned)gy < 128u) {
        const float* src = xb + (size_t)(h * 32 + cig * 8) * (HH * WW) + gy * WW + x_in;
        float2 f[8];
#pragma unroll
        for (int j = 0; j < 8; ++j) f[j] = *(const float2*)(src + (size_t)j * (HH * WW));
#pragma unroll
        for (int w = 0; w < 4; ++w) {
          pkA[w] = pack2bf(f[2 * w].x, f[2 * w + 1].x);
          pkB[w] = pack2bf(f[2 * w].y, f[2 * w + 1].y);
        }
      }
      int baseA = ((r * 68 + cc) * 64 + cig * 16) ^ (((cc ^ (cc >> 2)) & 3) << 4);
      int baseB = ((r * 68 + cc + 1) * 64 + cig * 16) ^ ((((cc + 1) ^ ((cc + 1) >> 2)) & 3) << 4);
      *(uint4*)(sb + baseA) = make_uint4(pkA[0], pkA[1], pkA[2], pkA[3]);
      *(uint4*)(sb + baseB) = make_uint4(pkB[0], pkB[1], pkB[2], pkB[3]);
    }
    // border cols c in {0, 65}: 48 items
    if (gtid < 48) {
      int cc  = (gtid & 1) ? 65 : 0;
      int cig = (gtid >> 1) & 3;
      int r   = gtid >> 3;         // 0..5
      int gy  = ybase + 4 * c - 1 + r;
      int x_in = x0 - 1 + cc;
      bool inb = ((unsigned)gy < 128u) & ((unsigned)x_in < 128u);
      unsigned int pk[4] = {0u, 0u, 0u, 0u};
      if (inb) {
        const float* src = xb + (size_t)(h * 32 + cig * 8) * (HH * WW) + gy * WW + x_in;
        float v[8];
#pragma unroll
        for (int j = 0; j < 8; ++j) v[j] = src[(size_t)j * (HH * WW)];
#pragma unroll
        for (int w = 0; w < 4; ++w) pk[w] = pack2bf(v[2 * w], v[2 * w + 1]);
      }
      int byte = ((r * 68 + cc) * 64 + cig * 16) ^ (((cc ^ (cc >> 2)) & 3) << 4);
      *(uint4*)(sb + byte) = make_uint4(pk[0], pk[1], pk[2], pk[3]);
    }
  };

  // ---- prologue: grpA stages (0,h0)->buf0, grpB stages (0,h1)->buf1 ----
  if (grp == 0) stage_to(0, 0, 0);
  else          stage_to(1, 0, 1);
  __syncthreads();  // also drains the weights DMA (vmcnt(0) before s_barrier)

  f32x4 acc[4][4];

#pragma unroll 1
  for (int p = 0; p < 16; ++p) {
    const int c = p >> 1, h = p & 1, buf = p % 3;
    if ((c & 1) == grp) {
      // ---- compute (c, h) from sbuf[buf] + wbuf (LDS-only path) ----
      if (h == 0) {
#pragma unroll
        for (int i = 0; i < 4; ++i)
#pragma unroll
          for (int j = 0; j < 4; ++j) acc[i][j] = (f32x4){0.f, 0.f, 0.f, 0.f};
      }
      const unsigned char* sb = lds + SB0 + buf * SBN;
#pragma unroll
      for (int tap = 0; tap < 9; ++tap) {
        const int ky = tap / 3, kx = tap - ky * 3;
        bf16x8 af[4];
#pragma unroll
        for (int cot = 0; cot < 4; ++cot)
          af[cot] = *(const bf16x8*)(lds + (h * 9 + tap) * 4096 + cot * 1024 + lane * 16);
        bf16x8 pf[4];
        const int r = wv + ky;
#pragma unroll
        for (int m = 0; m < 4; ++m) {
          int cc = m * 16 + pix + kx;
          int byte = ((r * 68 + cc) * 64 + g * 16) ^ (((cc ^ (cc >> 2)) & 3) << 4);
          pf[m] = *(const bf16x8*)(sb + byte);
        }
#pragma unroll
        for (int cot = 0; cot < 4; ++cot)
#pragma unroll
          for (int m = 0; m < 4; ++m)
            acc[cot][m] = __builtin_amdgcn_mfma_f32_16x16x32_bf16(af[cot], pf[m],
                                                                  acc[cot][m], 0, 0, 0);
      }
      if (h == 1) {
        // ---- store chunk c (direct, coalesced in 16-lane groups) ----
        const int y  = ybase + 4 * c + wv;
        const int cy = (y == 0) ? 0 : ((y == HH - 1) ? 2 : 1);
#pragma unroll
        for (int cot = 0; cot < 4; ++cot) {
#pragma unroll
          for (int m = 0; m < 4; ++m) {
            int xg = x0 + m * 16 + pix;
            int cx = (xg == 0) ? 0 : ((xg == WW - 1) ? 2 : 1);
#pragma unroll
            for (int j = 0; j < 4; ++j) {
              int co = cot * 16 + g * 4 + j;
              out[(((size_t)b * 64 + co) * HH + y) * WW + xg] =
                  acc[cot][m][j] + extb[co * 9 + cy * 3 + cx];
            }
          }
        }
      }
    } else {
      // ---- stage phase p+2's data (this group's own next chunk) ----
      const int p2 = p + 2;
      if (p2 < 16) stage_to(p2 % 3, p2 >> 1, p2 & 1);
    }
    __syncthreads();
  }
}

extern "C" void kernel_launch(void* const* d_in, const int* in_sizes, int n_in,
                              void* d_out, int out_size, void* d_ws, size_t ws_size,
                              hipStream_t stream) {
  const float* x        = (const float*)d_in[0];
  const float* extra_in = (const float*)d_in[1];
  const float* conv_w   = (const float*)d_in[2];
  const float* conv_b   = (const float*)d_in[3];
  const float* extra_w  = (const float*)d_in[4];
  const float* extra_b  = (const float*)d_in[5];
  float* out = (float*)d_out;

  unsigned short* wfrag = (unsigned short*)d_ws;              // 73728 B
  float* ext = (float*)((char*)d_ws + 73728);                 // 73728 B

  hipLaunchKernelGGL(prep_wfrag, dim3(144), dim3(256), 0, stream, conv_w, wfrag);
  hipLaunchKernelGGL(prep_ext,   dim3(8),   dim3(256), 0, stream,
                     extra_in, extra_w, conv_b, extra_b, ext);
  hipLaunchKernelGGL(conv_pc, dim3(2, 4, 32), dim3(512), 0, stream,
                     x, wfrag, ext, out);
}

// Round 11
// 72.948 us; speedup vs baseline: 1.2617x; 1.1867x over previous
//
#include <hip/hip_runtime.h>

#define HH 128
#define WW 128
#define SB0 73728              // sbuf region base (wbuf occupies [0, 73728))
#define SBN 26112              // per-buffer bytes: [6 r][68 c][32 ci] bf16

typedef __bf16 bf16x8 __attribute__((ext_vector_type(8)));
typedef __bf16 bf16x2 __attribute__((ext_vector_type(2)));
typedef float f32x4 __attribute__((ext_vector_type(4)));

static __device__ __forceinline__ unsigned short f2bf(float f) {
  unsigned int u = __float_as_uint(f);
  u = (u + 0x7FFFu + ((u >> 16) & 1u)) >> 16;  // RNE
  return (unsigned short)u;
}

static __device__ __forceinline__ unsigned int pack2bf(float lo, float hi) {
  bf16x2 v;
  v[0] = (__bf16)lo;
  v[1] = (__bf16)hi;
  return __builtin_bit_cast(unsigned int, v);
}

// ---------------------------------------------------------------------------
// Prep 1: pack conv_w [co][ci][tap] into MFMA A-fragment order (bf16):
//   wfrag[f = h*9+tap][cotile][lane][i] = conv_w[cotile*16 + lane%16]
//                                               [h*32 + (lane/16)*8 + i][tap]
// ---------------------------------------------------------------------------
__global__ __launch_bounds__(256) void prep_wfrag(const float* __restrict__ conv_w,
                                                  unsigned short* __restrict__ wfrag) {
  int tid = blockIdx.x * 256 + threadIdx.x;
  if (tid >= 18 * 2048) return;
  int i    = tid & 7;
  int lane = (tid >> 3) & 63;
  int cot  = (tid >> 9) & 3;
  int f    = tid >> 11;           // 0..17
  int h    = f / 9;               // ci half
  int tap  = f - h * 9;
  int co   = cot * 16 + (lane & 15);
  int ci   = h * 32 + (lane >> 4) * 8 + i;
  wfrag[tid] = f2bf(conv_w[(co * 64 + ci) * 9 + tap]);
}

// ---------------------------------------------------------------------------
// Prep 2: grouped conv of spatially-constant input -> 9-case boundary table
//   ext[b][co][cy][cx]  (includes conv_b + extra_b)
// ---------------------------------------------------------------------------
__global__ __launch_bounds__(256) void prep_ext(const float* __restrict__ extra_in,
                                                const float* __restrict__ extra_w,
                                                const float* __restrict__ conv_b,
                                                const float* __restrict__ extra_b,
                                                float* __restrict__ ext) {
  int t = blockIdx.x * 256 + threadIdx.x;
  if (t >= 32 * 64) return;
  int b = t >> 6, co = t & 63;
  float base = conv_b[co] + extra_b[co];
  float acc[3][3];
#pragma unroll
  for (int i = 0; i < 3; ++i)
#pragma unroll
    for (int j = 0; j < 3; ++j) acc[i][j] = 0.f;

#pragma unroll
  for (int f = 0; f < 3; ++f) {
    float e = extra_in[b * 192 + co * 3 + f];
    const float* w = extra_w + (co * 3 + f) * 9;
    float rs[3][3];
#pragma unroll
    for (int ky = 0; ky < 3; ++ky) {
      float w0 = w[ky * 3 + 0], w1 = w[ky * 3 + 1], w2 = w[ky * 3 + 2];
      rs[ky][0] = w1 + w2;
      rs[ky][1] = w0 + w1 + w2;
      rs[ky][2] = w0 + w1;
    }
#pragma unroll
    for (int cx = 0; cx < 3; ++cx) {
      acc[0][cx] += e * (rs[1][cx] + rs[2][cx]);
      acc[1][cx] += e * (rs[0][cx] + rs[1][cx] + rs[2][cx]);
      acc[2][cx] += e * (rs[0][cx] + rs[1][cx]);
    }
  }
#pragma unroll
  for (int cy = 0; cy < 3; ++cy)
#pragma unroll
    for (int cx = 0; cx < 3; ++cx)
      ext[t * 9 + cy * 3 + cx] = base + acc[cy][cx];
}

// ---------------------------------------------------------------------------
// Main: producer/consumer group ping-pong implicit-GEMM conv (r10 chassis).
// Changes vs r10 (both pure-BW levers, compute identical):
//  1) float4 QUAD staging: interior item = 4 px x 8 ci via 8 global_load_
//     dwordx4 (16 B/lane) -> half the load instructions, 2x outstanding
//     bytes. Borders unchanged (scalar).
//  2) XCD chunk swizzle: 256 wgs remapped so each XCD owns 32 consecutive
//     work items = 4 contiguous batches (16 MB region) -> DRAM page + L2
//     locality for concurrent blocks. Bijective (256 % 8 == 0).
// ---------------------------------------------------------------------------
__global__ __launch_bounds__(512, 1) void conv_pc(const float* __restrict__ x,
                                                  const unsigned short* __restrict__ wfrag,
                                                  const float* __restrict__ ext,
                                                  float* __restrict__ out) {
  // ---- XCD chunk swizzle: orig round-robins XCDs; give XCD k work chunk k ----
  const int orig = blockIdx.x + 2 * (blockIdx.y + 4 * blockIdx.z);  // 0..255
  const int work = (orig & 7) * 32 + (orig >> 3);
  const int xh    = work & 1;
  const int yq    = (work >> 1) & 3;
  const int b     = work >> 3;

  const int ybase = yq * 32;
  const int x0    = xh * 64;
  const int tid  = threadIdx.x;
  const int lane = tid & 63;
  const int wv8  = tid >> 6;        // 0..7
  const int grp  = wv8 >> 2;        // 0 = A, 1 = B
  const int wv   = wv8 & 3;         // row within chunk
  const int gtid = tid & 255;       // thread id within group
  const int pix  = lane & 15;
  const int g    = lane >> 4;

  __shared__ __align__(16) unsigned char lds[SB0 + 3 * SBN];  // 152064 B

  const float* xb   = x + (size_t)b * 64 * HH * WW;
  const float* extb = ext + (size_t)b * 64 * 9;

  // ---- weights: DMA 72 KB once (9 iters x 512 thr x 16B) ----
#pragma unroll
  for (int it = 0; it < 9; ++it) {
    int off = (tid + it * 512) * 16;
    __builtin_amdgcn_global_load_lds(
        (const __attribute__((address_space(1))) unsigned int*)((const char*)wfrag + off),
        (__attribute__((address_space(3))) unsigned int*)(lds + off), 16, 0, 0);
  }

  // ---- stage (chunk c, ci-half h) -> sbuf[buf], using one group's 256 thr ----
  auto stage_to = [&](int buf, int c, int h) {
    unsigned char* sb = lds + SB0 + buf * SBN;
    // interior: quad items (4 px x 8 ci): 16 quads x 4 cigs x 6 rows = 384
#pragma unroll
    for (int it = 0; it < 2; ++it) {
      int q = gtid + it * 256;
      if (q < 384) {
        int qd  = q & 15;            // quad index: cols 1+4qd .. 4+4qd
        int cig = (q >> 4) & 3;      // ci octet within half
        int r   = q >> 6;            // 0..5
        int gy  = ybase + 4 * c - 1 + r;
        int cc  = 1 + 4 * qd;
        int x_in = x0 + 4 * qd;      // 16B-aligned float4
        float4 f[8];
        if ((unsigned)gy < 128u) {
          const float* src = xb + (size_t)(h * 32 + cig * 8) * (HH * WW) + gy * WW + x_in;
#pragma unroll
          for (int j = 0; j < 8; ++j) f[j] = *(const float4*)(src + (size_t)j * (HH * WW));
        } else {
#pragma unroll
          for (int j = 0; j < 8; ++j) f[j] = make_float4(0.f, 0.f, 0.f, 0.f);
        }
#pragma unroll
        for (int p = 0; p < 4; ++p) {
          const int cp = cc + p;
          unsigned int pk[4];
#pragma unroll
          for (int w = 0; w < 4; ++w) {
            const float* lo = (const float*)&f[2 * w];
            const float* hi = (const float*)&f[2 * w + 1];
            pk[w] = pack2bf(lo[p], hi[p]);
          }
          int byte = ((r * 68 + cp) * 64 + cig * 16) ^ (((cp ^ (cp >> 2)) & 3) << 4);
          *(uint4*)(sb + byte) = make_uint4(pk[0], pk[1], pk[2], pk[3]);
        }
      }
    }
    // border cols c in {0, 65}: 48 items
    if (gtid < 48) {
      int cc  = (gtid & 1) ? 65 : 0;
      int cig = (gtid >> 1) & 3;
      int r   = gtid >> 3;         // 0..5
      int gy  = ybase + 4 * c - 1 + r;
      int x_in = x0 - 1 + cc;
      bool inb = ((unsigned)gy < 128u) & ((unsigned)x_in < 128u);
      unsigned int pk[4] = {0u, 0u, 0u, 0u};
      if (inb) {
        const float* src = xb + (size_t)(h * 32 + cig * 8) * (HH * WW) + gy * WW + x_in;
        float v[8];
#pragma unroll
        for (int j = 0; j < 8; ++j) v[j] = src[(size_t)j * (HH * WW)];
#pragma unroll
        for (int w = 0; w < 4; ++w) pk[w] = pack2bf(v[2 * w], v[2 * w + 1]);
      }
      int byte = ((r * 68 + cc) * 64 + cig * 16) ^ (((cc ^ (cc >> 2)) & 3) << 4);
      *(uint4*)(sb + byte) = make_uint4(pk[0], pk[1], pk[2], pk[3]);
    }
  };

  // ---- prologue: grpA stages (0,h0)->buf0, grpB stages (0,h1)->buf1 ----
  if (grp == 0) stage_to(0, 0, 0);
  else          stage_to(1, 0, 1);
  __syncthreads();  // also drains the weights DMA

  f32x4 acc[4][4];

#pragma unroll 1
  for (int p = 0; p < 16; ++p) {
    const int c = p >> 1, h = p & 1, buf = p % 3;
    if ((c & 1) == grp) {
      // ---- compute (c, h) from sbuf[buf] + wbuf (LDS-only path) ----
      if (h == 0) {
#pragma unroll
        for (int i = 0; i < 4; ++i)
#pragma unroll
          for (int j = 0; j < 4; ++j) acc[i][j] = (f32x4){0.f, 0.f, 0.f, 0.f};
      }
      const unsigned char* sb = lds + SB0 + buf * SBN;
#pragma unroll
      for (int tap = 0; tap < 9; ++tap) {
        const int ky = tap / 3, kx = tap - ky * 3;
        bf16x8 af[4];
#pragma unroll
        for (int cot = 0; cot < 4; ++cot)
          af[cot] = *(const bf16x8*)(lds + (h * 9 + tap) * 4096 + cot * 1024 + lane * 16);
        bf16x8 pf[4];
        const int r = wv + ky;
#pragma unroll
        for (int m = 0; m < 4; ++m) {
          int cc = m * 16 + pix + kx;
          int byte = ((r * 68 + cc) * 64 + g * 16) ^ (((cc ^ (cc >> 2)) & 3) << 4);
          pf[m] = *(const bf16x8*)(sb + byte);
        }
#pragma unroll
        for (int cot = 0; cot < 4; ++cot)
#pragma unroll
          for (int m = 0; m < 4; ++m)
            acc[cot][m] = __builtin_amdgcn_mfma_f32_16x16x32_bf16(af[cot], pf[m],
                                                                  acc[cot][m], 0, 0, 0);
      }
      if (h == 1) {
        // ---- store chunk c (direct, coalesced in 16-lane groups) ----
        const int y  = ybase + 4 * c + wv;
        const int cy = (y == 0) ? 0 : ((y == HH - 1) ? 2 : 1);
#pragma unroll
        for (int cot = 0; cot < 4; ++cot) {
#pragma unroll
          for (int m = 0; m < 4; ++m) {
            int xg = x0 + m * 16 + pix;
            int cx = (xg == 0) ? 0 : ((xg == WW - 1) ? 2 : 1);
#pragma unroll
            for (int j = 0; j < 4; ++j) {
              int co = cot * 16 + g * 4 + j;
              out[(((size_t)b * 64 + co) * HH + y) * WW + xg] =
                  acc[cot][m][j] + extb[co * 9 + cy * 3 + cx];
            }
          }
        }
      }
    } else {
      // ---- stage phase p+2's data (this group's own next chunk) ----
      const int p2 = p + 2;
      if (p2 < 16) stage_to(p2 % 3, p2 >> 1, p2 & 1);
    }
    __syncthreads();
  }
}

extern "C" void kernel_launch(void* const* d_in, const int* in_sizes, int n_in,
                              void* d_out, int out_size, void* d_ws, size_t ws_size,
                              hipStream_t stream) {
  const float* x        = (const float*)d_in[0];
  const float* extra_in = (const float*)d_in[1];
  const float* conv_w   = (const float*)d_in[2];
  const float* conv_b   = (const float*)d_in[3];
  const float* extra_w  = (const float*)d_in[4];
  const float* extra_b  = (const float*)d_in[5];
  float* out = (float*)d_out;

  unsigned short* wfrag = (unsigned short*)d_ws;              // 73728 B
  float* ext = (float*)((char*)d_ws + 73728);                 // 73728 B

  hipLaunchKernelGGL(prep_wfrag, dim3(144), dim3(256), 0, stream, conv_w, wfrag);
  hipLaunchKernelGGL(prep_ext,   dim3(8),   dim3(256), 0, stream,
                     extra_in, extra_w, conv_b, extra_b, ext);
  hipLaunchKernelGGL(conv_pc, dim3(2, 4, 32), dim3(512), 0, stream,
                     x, wfrag, ext, out);
}